// Round 2
// baseline (23.674 us; speedup 1.0000x reference)
//
#include <hip/hip_runtime.h>
#include <hip/hip_bf16.h>

typedef __attribute__((ext_vector_type(8))) short short8_t;
typedef __attribute__((ext_vector_type(4))) float f32x4;

static __device__ __forceinline__ unsigned short f2bf(float f) {
    unsigned int u = __float_as_uint(f);
    unsigned int r = u + 0x7fffu + ((u >> 16) & 1u);   // RNE (finite inputs)
    return (unsigned short)(r >> 16);
}

#define BM 128
#define BN 64
#define LDA 136   // bf16 elems per LDS row: 128 + 8 pad

// Fused: stage f32 -> bf16 in LDS + row norms, MFMA, epilogue.
// out[m][c] = 2*dot(x[m],P[c]) - xsq[m] - psq[c]  (= -||x-P||^2), c < 1000.
__global__ __launch_bounds__(256) void fused_kernel(
        const float* __restrict__ X,   // [8192][128] f32
        const float* __restrict__ P,   // [1000][128] f32
        float* __restrict__ out) {     // [8192][1000] f32
    __shared__ unsigned short As[BM][LDA];
    __shared__ unsigned short Bs[BN][LDA];
    __shared__ float xq_s[BM];
    __shared__ float pq_s[BN];

    int t = threadIdx.x;
    int bn = blockIdx.x & 15;        // 16 N-tiles (fast-varying: consecutive blocks share A rows in L2)
    int bm = blockIdx.x >> 4;        // 64 M-tiles
    const int rowA0 = bm * BM;
    const int rowB0 = bn * BN;

    // Stage A tile: 128 rows x 128 f32 -> bf16, 16 threads/row, 8 elems/thread.
    #pragma unroll
    for (int it = 0; it < 8; ++it) {
        int idx = it * 256 + t;
        int r = idx >> 4;
        int c8 = (idx & 15) * 8;
        const float4* src = reinterpret_cast<const float4*>(X + (size_t)(rowA0 + r) * 128 + c8);
        float4 v0 = src[0], v1 = src[1];
        short8_t b;
        b[0] = (short)f2bf(v0.x); b[1] = (short)f2bf(v0.y);
        b[2] = (short)f2bf(v0.z); b[3] = (short)f2bf(v0.w);
        b[4] = (short)f2bf(v1.x); b[5] = (short)f2bf(v1.y);
        b[6] = (short)f2bf(v1.z); b[7] = (short)f2bf(v1.w);
        *reinterpret_cast<short8_t*>(&As[r][c8]) = b;
        float s = v0.x*v0.x + v0.y*v0.y + v0.z*v0.z + v0.w*v0.w
                + v1.x*v1.x + v1.y*v1.y + v1.z*v1.z + v1.w*v1.w;
        s += __shfl_xor(s, 1, 64);
        s += __shfl_xor(s, 2, 64);
        s += __shfl_xor(s, 4, 64);
        s += __shfl_xor(s, 8, 64);
        if ((t & 15) == 0) xq_s[r] = s;
    }
    // Stage B tile: 64 rows x 128 f32 -> bf16 (rows >= 1000 zero-filled).
    #pragma unroll
    for (int it = 0; it < 4; ++it) {
        int idx = it * 256 + t;
        int r = idx >> 4;
        int c8 = (idx & 15) * 8;
        int gr = rowB0 + r;
        float4 v0 = make_float4(0.f, 0.f, 0.f, 0.f);
        float4 v1 = make_float4(0.f, 0.f, 0.f, 0.f);
        if (gr < 1000) {
            const float4* src = reinterpret_cast<const float4*>(P + (size_t)gr * 128 + c8);
            v0 = src[0]; v1 = src[1];
        }
        short8_t b;
        b[0] = (short)f2bf(v0.x); b[1] = (short)f2bf(v0.y);
        b[2] = (short)f2bf(v0.z); b[3] = (short)f2bf(v0.w);
        b[4] = (short)f2bf(v1.x); b[5] = (short)f2bf(v1.y);
        b[6] = (short)f2bf(v1.z); b[7] = (short)f2bf(v1.w);
        *reinterpret_cast<short8_t*>(&Bs[r][c8]) = b;
        float s = v0.x*v0.x + v0.y*v0.y + v0.z*v0.z + v0.w*v0.w
                + v1.x*v1.x + v1.y*v1.y + v1.z*v1.z + v1.w*v1.w;
        s += __shfl_xor(s, 1, 64);
        s += __shfl_xor(s, 2, 64);
        s += __shfl_xor(s, 4, 64);
        s += __shfl_xor(s, 8, 64);
        if ((t & 15) == 0) pq_s[r] = s;
    }
    __syncthreads();

    int wave = t >> 6;
    int lane = t & 63;
    int wm = (wave >> 1) * 64;   // wave M offset: 0 / 64
    int wn = (wave & 1) * 32;    // wave N offset: 0 / 32
    int lr = lane & 15;
    int lk = (lane >> 4) * 8;

    f32x4 acc[4][2] = {};
    #pragma unroll
    for (int ks = 0; ks < 4; ++ks) {
        int k0 = ks * 32 + lk;
        short8_t a[4], b[2];
        #pragma unroll
        for (int mi = 0; mi < 4; ++mi)
            a[mi] = *reinterpret_cast<const short8_t*>(&As[wm + mi * 16 + lr][k0]);
        #pragma unroll
        for (int ni = 0; ni < 2; ++ni)
            b[ni] = *reinterpret_cast<const short8_t*>(&Bs[wn + ni * 16 + lr][k0]);
        #pragma unroll
        for (int mi = 0; mi < 4; ++mi)
            #pragma unroll
            for (int ni = 0; ni < 2; ++ni)
                acc[mi][ni] = __builtin_amdgcn_mfma_f32_16x16x32_bf16(
                        a[mi], b[ni], acc[mi][ni], 0, 0, 0);
    }

    // Epilogue: C/D layout col=lane&15, row=(lane>>4)*4+j  [m89]
    int mrow_base = (lane >> 4) * 4;
    #pragma unroll
    for (int mi = 0; mi < 4; ++mi) {
        #pragma unroll
        for (int ni = 0; ni < 2; ++ni) {
            int cl = wn + ni * 16 + lr;
            int c = rowB0 + cl;
            if (c < 1000) {
                float pq = pq_s[cl];
                #pragma unroll
                for (int j = 0; j < 4; ++j) {
                    int ml = wm + mi * 16 + mrow_base + j;
                    int m = rowA0 + ml;
                    out[(size_t)m * 1000 + c] = 2.f * acc[mi][ni][j] - xq_s[ml] - pq;
                }
            }
        }
    }
}

extern "C" void kernel_launch(void* const* d_in, const int* in_sizes, int n_in,
                              void* d_out, int out_size, void* d_ws, size_t ws_size,
                              hipStream_t stream) {
    const float* x = (const float*)d_in[0];   // (8192, 128) f32
    const float* p = (const float*)d_in[1];   // (1000, 128) f32
    float* out = (float*)d_out;               // (8192, 1000) f32
    (void)d_ws; (void)ws_size;
    fused_kernel<<<1024, 256, 0, stream>>>(x, p, out);
}